// Round 1
// baseline (339.759 us; speedup 1.0000x reference)
//
#include <hip/hip_runtime.h>

typedef __bf16 bf16x8 __attribute__((ext_vector_type(8)));
typedef float f32x4 __attribute__((ext_vector_type(4)));

#define D 64          // node/edge feature dim and hidden dim
#define NEG_SLOPE 0.01f
#define BN_EPS 1e-5f

static __device__ __forceinline__ unsigned short f2bf(float f) {
    unsigned u = __builtin_bit_cast(unsigned, f);
    unsigned r = (u + 0x7fffu + ((u >> 16) & 1u)) >> 16;
    return (unsigned short)r;
}

// ---------------- f32 -> bf16 conversion (vectorized) ----------------
__global__ __launch_bounds__(256) void cvt_bf16(const float* __restrict__ in,
                                                unsigned short* __restrict__ outp, int n4) {
    int idx = blockIdx.x * 256 + threadIdx.x;
    if (idx >= n4) return;
    const f32x4 v = *reinterpret_cast<const f32x4*>(in + (size_t)idx * 4);
    ushort4 u;
    u.x = f2bf(v.x); u.y = f2bf(v.y); u.z = f2bf(v.z); u.w = f2bf(v.w);
    *reinterpret_cast<ushort4*>(outp + (size_t)idx * 4) = u;
}

// ---------------- out[n,o] = sum_i x[n,i]*M[i,o] (+bias[o]) ----------------
// M row-major [64][64]. Used for root term (into aggr) and node-bias NB.
__global__ __launch_bounds__(256) void node_mm(const float* __restrict__ x,
                                               const float* __restrict__ M,
                                               const float* __restrict__ bias,
                                               float* __restrict__ out, int useBias) {
    __shared__ float Ml[64][64];
    __shared__ float xl[64][64];
    const int tid = threadIdx.x;
    const int n0 = blockIdx.x * 64;
    for (int f = tid; f < 1024; f += 256) {
        int r = f >> 4, c = f & 15;
        *reinterpret_cast<float4*>(&Ml[r][c * 4]) =
            *reinterpret_cast<const float4*>(M + (size_t)r * 64 + c * 4);
        *reinterpret_cast<float4*>(&xl[r][c * 4]) =
            *reinterpret_cast<const float4*>(x + (size_t)(n0 + r) * 64 + c * 4);
    }
    __syncthreads();
    const int o = tid & 63, g = tid >> 6;
    float acc[16] = {};
    for (int i4 = 0; i4 < 16; ++i4) {
        float m0 = Ml[4 * i4 + 0][o], m1 = Ml[4 * i4 + 1][o];
        float m2 = Ml[4 * i4 + 2][o], m3 = Ml[4 * i4 + 3][o];
#pragma unroll
        for (int k = 0; k < 16; ++k) {
            const f32x4 xv = *reinterpret_cast<const f32x4*>(&xl[g + 4 * k][4 * i4]);
            acc[k] += xv.x * m0 + xv.y * m1 + xv.z * m2 + xv.w * m3;
        }
    }
    const float b = useBias ? bias[o] : 0.f;
#pragma unroll
    for (int k = 0; k < 16; ++k)
        out[(size_t)(n0 + g + 4 * k) * 64 + o] = acc[k] + b;
}

// ---------------- fused per-edge NNConv message + scatter-add ----------------
// msg[e,o] = sum_i x[src[e],i] * (sum_d ef[e,d]*W[i*64+o,d]) + NB[src[e],o]
// atomicAdd into aggr[dst[e],o]. 64 edges/block, 4 waves, MFMA 16x16x32 bf16.
__global__ __launch_bounds__(256) void msg_kernel(
    const unsigned short* __restrict__ ef_b,   // [E][64] bf16
    const unsigned short* __restrict__ wb,     // [4096][64] bf16, row q=i*64+o
    const float* __restrict__ x,               // [N][64]
    const float* __restrict__ NB,              // [N][64]
    const int* __restrict__ src,
    const int* __restrict__ dst,
    float* __restrict__ aggr) {                // [N][64]
    __shared__ float xT[64][64];               // xT[i][e_local] = x[src[e]][i]
    const int tid = threadIdx.x;
    const int e0 = blockIdx.x * 64;

    // stage x rows (gather by src), transposed for b128 broadcast reads
#pragma unroll
    for (int it = 0; it < 4; ++it) {
        int f = it * 256 + tid;
        int e = f & 63, c = f >> 6;            // c in 0..15
        int s = src[e0 + e];
        const f32x4 xv = *reinterpret_cast<const f32x4*>(x + (size_t)s * 64 + c * 4);
        xT[4 * c + 0][e] = xv.x;
        xT[4 * c + 1][e] = xv.y;
        xT[4 * c + 2][e] = xv.z;
        xT[4 * c + 3][e] = xv.w;
    }
    __syncthreads();

    const int w = tid >> 6;        // wave 0..3 -> edge rows 16w..16w+15
    const int l = tid & 63;
    const int lg = l >> 4;         // k-group
    const int ln = l & 15;

    const size_t erow = (size_t)(e0 + 16 * w + ln) * 64;
    const bf16x8 A0 = *reinterpret_cast<const bf16x8*>(ef_b + erow + 8 * lg);
    const bf16x8 A1 = *reinterpret_cast<const bf16x8*>(ef_b + erow + 8 * lg + 32);

    f32x4 msg[4] = {};
    for (int i = 0; i < 64; ++i) {
        const f32x4 xv = *reinterpret_cast<const f32x4*>(&xT[i][16 * w + 4 * lg]);
        const unsigned short* wrow = wb + ((size_t)i * 64 + ln) * 64 + 8 * lg;
#pragma unroll
        for (int ot = 0; ot < 4; ++ot) {
            const bf16x8 B0 = *reinterpret_cast<const bf16x8*>(wrow + (size_t)16 * ot * 64);
            const bf16x8 B1 = *reinterpret_cast<const bf16x8*>(wrow + (size_t)16 * ot * 64 + 32);
            f32x4 m = {};
            m = __builtin_amdgcn_mfma_f32_16x16x32_bf16(A0, B0, m, 0, 0, 0);
            m = __builtin_amdgcn_mfma_f32_16x16x32_bf16(A1, B1, m, 0, 0, 0);
            msg[ot] += xv * m;     // elementwise: row r pairs with xv component r
        }
    }

    // add per-node bias term and scatter
#pragma unroll
    for (int r = 0; r < 4; ++r) {
        const int e = e0 + 16 * w + 4 * lg + r;
        const int s = src[e], d = dst[e];
#pragma unroll
        for (int ot = 0; ot < 4; ++ot) {
            const int o = 16 * ot + ln;
            atomicAdd(aggr + (size_t)d * 64 + o, msg[ot][r] + NB[(size_t)s * 64 + o]);
        }
    }
}

// ---------------- BN statistics (sum, sumsq per channel) ----------------
__global__ __launch_bounds__(256) void bn_stats(const float* __restrict__ h,
                                                float* __restrict__ sums) {
    const int tid = threadIdx.x;
    const int o = tid & 63, g = tid >> 6;
    const int n0 = blockIdx.x * 128;
    float s = 0.f, s2 = 0.f;
    for (int k = 0; k < 32; ++k) {
        float v = h[(size_t)(n0 + g * 32 + k) * 64 + o];
        s += v; s2 += v * v;
    }
    __shared__ float red[2][4][64];
    red[0][g][o] = s; red[1][g][o] = s2;
    __syncthreads();
    if (g == 0) {
        s  = red[0][0][o] + red[0][1][o] + red[0][2][o] + red[0][3][o];
        s2 = red[1][0][o] + red[1][1][o] + red[1][2][o] + red[1][3][o];
        atomicAdd(&sums[o], s);
        atomicAdd(&sums[64 + o], s2);
    }
}

__global__ void bn_finalize(const float* __restrict__ sums,
                            const float* __restrict__ gamma,
                            const float* __restrict__ beta,
                            float* __restrict__ ss, float invN) {
    const int o = threadIdx.x;   // 64 threads
    float mean = sums[o] * invN;
    float var = sums[64 + o] * invN - mean * mean;
    float sc = gamma[o] * rsqrtf(var + BN_EPS);
    ss[o] = sc;
    ss[64 + o] = beta[o] - mean * sc;
}

__global__ __launch_bounds__(256) void bn_apply(const float* __restrict__ h,
                                                const float* __restrict__ ss,
                                                float* __restrict__ out, int total4) {
    const int idx = blockIdx.x * 256 + threadIdx.x;
    if (idx >= total4) return;
    const f32x4 v = *reinterpret_cast<const f32x4*>(h + (size_t)idx * 4);
    const int o0 = (idx * 4) & 63;
    const f32x4 sc = *reinterpret_cast<const f32x4*>(ss + o0);
    const f32x4 sh = *reinterpret_cast<const f32x4*>(ss + 64 + o0);
    f32x4 r = v * sc + sh;
    f32x4 res;
    res.x = fmaxf(r.x, 0.f) + NEG_SLOPE * fminf(r.x, 0.f);
    res.y = fmaxf(r.y, 0.f) + NEG_SLOPE * fminf(r.y, 0.f);
    res.z = fmaxf(r.z, 0.f) + NEG_SLOPE * fminf(r.z, 0.f);
    res.w = fmaxf(r.w, 0.f) + NEG_SLOPE * fminf(r.w, 0.f);
    *reinterpret_cast<f32x4*>(out + (size_t)idx * 4) = res;
}

// ---------------- final: out[n,q] = sum_o x[n,o]*W_lin[q,o] + b_lin[q] ----------------
__global__ __launch_bounds__(256) void out_kernel(const float* __restrict__ x2,
                                                  const float* __restrict__ Wl,
                                                  const float* __restrict__ bl,
                                                  float* __restrict__ out) {
    __shared__ float Wt[64][129];   // Wt[o][q], padded to avoid bank conflicts
    __shared__ float xl[64][64];
    const int tid = threadIdx.x;
    const int n0 = blockIdx.x * 64;
    for (int f = tid; f < 8192; f += 256) {
        int q = f >> 6, o = f & 63;          // coalesced global read of Wl
        Wt[o][q] = Wl[f];
    }
    for (int f = tid; f < 1024; f += 256) {
        int r = f >> 4, c = f & 15;
        *reinterpret_cast<float4*>(&xl[r][c * 4]) =
            *reinterpret_cast<const float4*>(x2 + (size_t)(n0 + r) * 64 + c * 4);
    }
    __syncthreads();
    const int q = tid & 127, ng = tid >> 7;
    float acc[32] = {};
    for (int o4 = 0; o4 < 16; ++o4) {
        float w0 = Wt[4 * o4 + 0][q], w1 = Wt[4 * o4 + 1][q];
        float w2 = Wt[4 * o4 + 2][q], w3 = Wt[4 * o4 + 3][q];
#pragma unroll
        for (int k = 0; k < 32; ++k) {
            const f32x4 xv = *reinterpret_cast<const f32x4*>(&xl[ng + 2 * k][4 * o4]);
            acc[k] += xv.x * w0 + xv.y * w1 + xv.z * w2 + xv.w * w3;
        }
    }
    const float b = bl[q];
#pragma unroll
    for (int k = 0; k < 32; ++k)
        out[(size_t)(n0 + ng + 2 * k) * 128 + q] = acc[k] + b;
}

extern "C" void kernel_launch(void* const* d_in, const int* in_sizes, int n_in,
                              void* d_out, int out_size, void* d_ws, size_t ws_size,
                              hipStream_t stream) {
    const float* nf      = (const float*)d_in[0];
    const int*   ei      = (const int*)d_in[1];
    const float* ef      = (const float*)d_in[2];
    const float* W_edge0 = (const float*)d_in[4];
    const float* b_edge0 = (const float*)d_in[5];
    const float* W_root0 = (const float*)d_in[6];
    const float* b_root0 = (const float*)d_in[7];
    const float* gamma0  = (const float*)d_in[8];
    const float* beta0   = (const float*)d_in[9];
    const float* W_edge1 = (const float*)d_in[10];
    const float* b_edge1 = (const float*)d_in[11];
    const float* W_root1 = (const float*)d_in[12];
    const float* b_root1 = (const float*)d_in[13];
    const float* gamma1  = (const float*)d_in[14];
    const float* beta1   = (const float*)d_in[15];
    const float* W_lin   = (const float*)d_in[16];
    const float* b_lin   = (const float*)d_in[17];

    const int N = in_sizes[0] / D;    // 8192
    const int E = in_sizes[1] / 2;    // 32768
    const int* src = ei;
    const int* dst = ei + E;

    char* ws = (char*)d_ws;
    unsigned short* ef_b  = (unsigned short*)ws;                       // E*64 bf16
    unsigned short* we_b0 = ef_b + (size_t)E * 64;                     // 4096*64 bf16
    unsigned short* we_b1 = we_b0 + (size_t)4096 * 64;
    float* aggr0 = (float*)(we_b1 + (size_t)4096 * 64);
    float* nb    = aggr0 + (size_t)N * 64;
    float* x1    = nb    + (size_t)N * 64;
    float* aggr1 = x1    + (size_t)N * 64;
    float* x2    = aggr1 + (size_t)N * 64;
    float* stats = x2    + (size_t)N * 64;   // 128 floats
    float* ssbuf = stats + 128;              // 128 floats

    const float invN = 1.0f / (float)N;

    // bf16 conversions (ef shared by both layers)
    cvt_bf16<<<(E * 64 / 4 + 255) / 256, 256, 0, stream>>>(ef, ef_b, E * 64 / 4);
    cvt_bf16<<<(4096 * 64 / 4 + 255) / 256, 256, 0, stream>>>(W_edge0, we_b0, 4096 * 64 / 4);
    cvt_bf16<<<(4096 * 64 / 4 + 255) / 256, 256, 0, stream>>>(W_edge1, we_b1, 4096 * 64 / 4);

    // ---- layer 0 ----
    node_mm<<<N / 64, 256, 0, stream>>>(nf, W_root0, b_root0, aggr0, 1);   // aggr0 = x@W_root + b_root
    node_mm<<<N / 64, 256, 0, stream>>>(nf, b_edge0, nullptr, nb, 0);      // NB = x@reshape(b_edge)
    msg_kernel<<<E / 64, 256, 0, stream>>>(ef_b, we_b0, nf, nb, src, dst, aggr0);
    hipMemsetAsync(stats, 0, 128 * sizeof(float), stream);
    bn_stats<<<N / 128, 256, 0, stream>>>(aggr0, stats);
    bn_finalize<<<1, 64, 0, stream>>>(stats, gamma0, beta0, ssbuf, invN);
    bn_apply<<<(N * 64 / 4 + 255) / 256, 256, 0, stream>>>(aggr0, ssbuf, x1, N * 64 / 4);

    // ---- layer 1 ----
    node_mm<<<N / 64, 256, 0, stream>>>(x1, W_root1, b_root1, aggr1, 1);
    node_mm<<<N / 64, 256, 0, stream>>>(x1, b_edge1, nullptr, nb, 0);
    msg_kernel<<<E / 64, 256, 0, stream>>>(ef_b, we_b1, x1, nb, src, dst, aggr1);
    hipMemsetAsync(stats, 0, 128 * sizeof(float), stream);
    bn_stats<<<N / 128, 256, 0, stream>>>(aggr1, stats);
    bn_finalize<<<1, 64, 0, stream>>>(stats, gamma1, beta1, ssbuf, invN);
    bn_apply<<<(N * 64 / 4 + 255) / 256, 256, 0, stream>>>(aggr1, ssbuf, x2, N * 64 / 4);

    // ---- final linear ----
    out_kernel<<<N / 64, 256, 0, stream>>>(x2, W_lin, b_lin, (float*)d_out);
}

// Round 2
// 193.071 us; speedup vs baseline: 1.7598x; 1.7598x over previous
//
#include <hip/hip_runtime.h>

typedef __bf16 bf16x8 __attribute__((ext_vector_type(8)));
typedef float f32x4 __attribute__((ext_vector_type(4)));

#define NEG_SLOPE 0.01f
#define BN_EPS 1e-5f

static __device__ __forceinline__ unsigned short f2bf(float f) {
    unsigned u = __builtin_bit_cast(unsigned, f);
    unsigned r = (u + 0x7fffu + ((u >> 16) & 1u)) >> 16;
    return (unsigned short)r;
}
static __device__ __forceinline__ float bflo(unsigned u) {
    return __builtin_bit_cast(float, u << 16);
}
static __device__ __forceinline__ float bfhi(unsigned u) {
    return __builtin_bit_cast(float, u & 0xffff0000u);
}

// ---- convert ef (na4 float4-groups) and nf to bf16, one launch ----
__global__ __launch_bounds__(256) void cvt_two(const float* __restrict__ a,
                                               unsigned short* __restrict__ ab, int na4,
                                               const float* __restrict__ b,
                                               unsigned short* __restrict__ bb) {
    int idx = blockIdx.x * 256 + threadIdx.x;
    const float* in; unsigned short* outp; int i;
    if (idx < na4) { in = a; outp = ab; i = idx; }
    else           { in = b; outp = bb; i = idx - na4; }
    const f32x4 v = *reinterpret_cast<const f32x4*>(in + (size_t)i * 4);
    ushort4 u;
    u.x = f2bf(v.x); u.y = f2bf(v.y); u.z = f2bf(v.z); u.w = f2bf(v.w);
    *reinterpret_cast<ushort4*>(outp + (size_t)i * 4) = u;
}

// ---- build wfT[4224][64] bf16 for both layers in one launch ----
// rows 0..4095:   wfT[(o*64+d)][i] = W_edge[(i*64+o)*64 + d]
// rows 4096..4159: wfT[4096+o][i]  = W_root[i*64+o]
// rows 4160..4223: wfT[4160+o][i]  = b_edge[i*64+o]
__global__ __launch_bounds__(256) void build_wfT(
    const float* __restrict__ We0, const float* __restrict__ Wr0, const float* __restrict__ be0,
    unsigned short* __restrict__ T0,
    const float* __restrict__ We1, const float* __restrict__ Wr1, const float* __restrict__ be1,
    unsigned short* __restrict__ T1) {
    int g = blockIdx.x * 256 + threadIdx.x;      // 0 .. 2*270336-1
    const float *We, *Wr, *be; unsigned short* T; int idx;
    if (g < 270336) { We = We0; Wr = Wr0; be = be0; T = T0; idx = g; }
    else            { We = We1; Wr = Wr1; be = be1; T = T1; idx = g - 270336; }
    int i = idx & 63, rho = idx >> 6;
    float v;
    if (rho < 4096) { int o = rho >> 6, d = rho & 63; v = We[((((size_t)i << 6) | o) << 6) | d]; }
    else if (rho < 4160) { int o = rho - 4096; v = Wr[(i << 6) | o]; }
    else { int o = rho - 4160; v = be[(i << 6) | o]; }
    T[idx] = f2bf(v);
}

// ---- G-GEMM: [N,64]x[64,4224] -> G bf16 [N,4096] | aggr=root+b_root | NB ----
// grid (N/256, 66). Block 256 thr / 4 waves; wave w handles rows n0+64w..+63.
__global__ __launch_bounds__(256) void g_gemm(
    const unsigned short* __restrict__ xb,    // [N][64] bf16
    const unsigned short* __restrict__ wfT,   // [4224][64] bf16
    const float* __restrict__ b_root,         // [64]
    unsigned short* __restrict__ G,           // [N][4096] bf16
    float* __restrict__ aggr,                 // [N][64] f32
    float* __restrict__ NB,                   // [N][64] f32
    float* __restrict__ stats) {              // [128] zeroed here
    const int tid = threadIdx.x;
    const int w = tid >> 6, l = tid & 63, lg = l >> 4, ln = l & 15;
    const int bc = blockIdx.y;
    const int n0 = blockIdx.x * 256;
    if (bc == 64 && blockIdx.x == 0 && tid < 128) stats[tid] = 0.f;

    const unsigned short* brow = wfT + ((size_t)(bc * 64 + ln) * 64) + 8 * lg;
    bf16x8 B0[4], B1[4];
#pragma unroll
    for (int ot = 0; ot < 4; ++ot) {
        B0[ot] = *reinterpret_cast<const bf16x8*>(brow + ot * 16 * 64);
        B1[ot] = *reinterpret_cast<const bf16x8*>(brow + ot * 16 * 64 + 32);
    }
    const int r0 = n0 + 64 * w;
#pragma unroll
    for (int mt = 0; mt < 4; ++mt) {
        const unsigned short* arow = xb + (size_t)(r0 + 16 * mt + ln) * 64 + 8 * lg;
        const bf16x8 A0 = *reinterpret_cast<const bf16x8*>(arow);
        const bf16x8 A1 = *reinterpret_cast<const bf16x8*>(arow + 32);
#pragma unroll
        for (int ot = 0; ot < 4; ++ot) {
            f32x4 c = {};
            c = __builtin_amdgcn_mfma_f32_16x16x32_bf16(A0, B0[ot], c, 0, 0, 0);
            c = __builtin_amdgcn_mfma_f32_16x16x32_bf16(A1, B1[ot], c, 0, 0, 0);
            const int cl = 16 * ot + ln;
            if (bc < 64) {
#pragma unroll
                for (int rr = 0; rr < 4; ++rr) {
                    const int row = r0 + 16 * mt + 4 * lg + rr;
                    G[(size_t)row * 4096 + 64 * bc + cl] = f2bf(c[rr]);
                }
            } else if (bc == 64) {
                const float br = b_root[cl];
#pragma unroll
                for (int rr = 0; rr < 4; ++rr) {
                    const int row = r0 + 16 * mt + 4 * lg + rr;
                    aggr[(size_t)row * 64 + cl] = c[rr] + br;
                }
            } else {
#pragma unroll
                for (int rr = 0; rr < 4; ++rr) {
                    const int row = r0 + 16 * mt + 4 * lg + rr;
                    NB[(size_t)row * 64 + cl] = c[rr];
                }
            }
        }
    }
}

// ---- per-edge: msg[e,o] = sum_d ef[e,d]*G[src[e],o*64+d] + NB[src[e],o] ----
// atomicAdd into aggr[dst[e],o]. 32 edges/block, wave w -> edges 8w..8w+7.
__global__ __launch_bounds__(256) void edge_dot(
    const unsigned short* __restrict__ ef_b,  // [E][64] bf16
    const unsigned short* __restrict__ G,     // [N][4096] bf16
    const float* __restrict__ NB,             // [N][64] f32
    const int* __restrict__ src,
    const int* __restrict__ dst,
    float* __restrict__ aggr) {
    __shared__ unsigned short efs[32][64];
    const int tid = threadIdx.x;
    const int e0 = blockIdx.x * 32;
    {
        int e = tid >> 3, c8 = tid & 7;
        *reinterpret_cast<bf16x8*>(&efs[e][c8 * 8]) =
            *reinterpret_cast<const bf16x8*>(ef_b + (size_t)(e0 + e) * 64 + c8 * 8);
    }
    __syncthreads();
    const int w = tid >> 6, o = tid & 63;
    int ss[8], dd[8];
#pragma unroll
    for (int j = 0; j < 8; ++j) {
        ss[j] = src[e0 + 8 * w + j];
        dd[j] = dst[e0 + 8 * w + j];
    }
#pragma unroll 2
    for (int j = 0; j < 8; ++j) {
        const unsigned short* grow = G + (size_t)ss[j] * 4096 + (size_t)o * 64;
        float a0 = 0.f, a1 = 0.f;
#pragma unroll
        for (int c = 0; c < 8; ++c) {
            const uint4 gu = *reinterpret_cast<const uint4*>(grow + 8 * c);
            const uint4 fu = *reinterpret_cast<const uint4*>(&efs[8 * w + j][8 * c]);
            a0 += bflo(gu.x) * bflo(fu.x); a1 += bfhi(gu.x) * bfhi(fu.x);
            a0 += bflo(gu.y) * bflo(fu.y); a1 += bfhi(gu.y) * bfhi(fu.y);
            a0 += bflo(gu.z) * bflo(fu.z); a1 += bfhi(gu.z) * bfhi(fu.z);
            a0 += bflo(gu.w) * bflo(fu.w); a1 += bfhi(gu.w) * bfhi(fu.w);
        }
        const float acc = a0 + a1 + NB[(size_t)ss[j] * 64 + o];
        atomicAdd(aggr + (size_t)dd[j] * 64 + o, acc);
    }
}

// ---- BN statistics ----
__global__ __launch_bounds__(256) void bn_stats(const float* __restrict__ h,
                                                float* __restrict__ sums) {
    const int tid = threadIdx.x;
    const int o = tid & 63, g = tid >> 6;
    const int n0 = blockIdx.x * 128;
    float s = 0.f, s2 = 0.f;
    for (int k = 0; k < 32; ++k) {
        float v = h[(size_t)(n0 + g * 32 + k) * 64 + o];
        s += v; s2 += v * v;
    }
    __shared__ float red[2][4][64];
    red[0][g][o] = s; red[1][g][o] = s2;
    __syncthreads();
    if (g == 0) {
        s  = red[0][0][o] + red[0][1][o] + red[0][2][o] + red[0][3][o];
        s2 = red[1][0][o] + red[1][1][o] + red[1][2][o] + red[1][3][o];
        atomicAdd(&sums[o], s);
        atomicAdd(&sums[64 + o], s2);
    }
}

__global__ void bn_finalize(const float* __restrict__ sums,
                            const float* __restrict__ gamma,
                            const float* __restrict__ beta,
                            float* __restrict__ ss, float invN) {
    const int o = threadIdx.x;   // 64 threads
    float mean = sums[o] * invN;
    float var = sums[64 + o] * invN - mean * mean;
    float sc = gamma[o] * rsqrtf(var + BN_EPS);
    ss[o] = sc;
    ss[64 + o] = beta[o] - mean * sc;
}

// ---- BN apply + LeakyReLU, writes f32 and bf16 copies ----
__global__ __launch_bounds__(256) void bn_apply2(const float* __restrict__ h,
                                                 const float* __restrict__ ss,
                                                 float* __restrict__ outf,
                                                 unsigned short* __restrict__ outb,
                                                 int total4) {
    const int idx = blockIdx.x * 256 + threadIdx.x;
    if (idx >= total4) return;
    const f32x4 v = *reinterpret_cast<const f32x4*>(h + (size_t)idx * 4);
    const int o0 = (idx * 4) & 63;
    const f32x4 sc = *reinterpret_cast<const f32x4*>(ss + o0);
    const f32x4 sh = *reinterpret_cast<const f32x4*>(ss + 64 + o0);
    f32x4 r = v * sc + sh;
    f32x4 res;
    res.x = fmaxf(r.x, 0.f) + NEG_SLOPE * fminf(r.x, 0.f);
    res.y = fmaxf(r.y, 0.f) + NEG_SLOPE * fminf(r.y, 0.f);
    res.z = fmaxf(r.z, 0.f) + NEG_SLOPE * fminf(r.z, 0.f);
    res.w = fmaxf(r.w, 0.f) + NEG_SLOPE * fminf(r.w, 0.f);
    *reinterpret_cast<f32x4*>(outf + (size_t)idx * 4) = res;
    ushort4 u;
    u.x = f2bf(res.x); u.y = f2bf(res.y); u.z = f2bf(res.z); u.w = f2bf(res.w);
    *reinterpret_cast<ushort4*>(outb + (size_t)idx * 4) = u;
}

// ---- final: out[n,q] = sum_o x[n,o]*W_lin[q,o] + b_lin[q] ----
__global__ __launch_bounds__(256) void out_kernel(const float* __restrict__ x2,
                                                  const float* __restrict__ Wl,
                                                  const float* __restrict__ bl,
                                                  float* __restrict__ out) {
    __shared__ float Wt[64][129];
    __shared__ float xl[64][64];
    const int tid = threadIdx.x;
    const int n0 = blockIdx.x * 64;
    for (int f = tid; f < 8192; f += 256) {
        int q = f >> 6, o = f & 63;
        Wt[o][q] = Wl[f];
    }
    for (int f = tid; f < 1024; f += 256) {
        int r = f >> 4, c = f & 15;
        *reinterpret_cast<float4*>(&xl[r][c * 4]) =
            *reinterpret_cast<const float4*>(x2 + (size_t)(n0 + r) * 64 + c * 4);
    }
    __syncthreads();
    const int q = tid & 127, ng = tid >> 7;
    float acc[32] = {};
    for (int o4 = 0; o4 < 16; ++o4) {
        float w0 = Wt[4 * o4 + 0][q], w1 = Wt[4 * o4 + 1][q];
        float w2 = Wt[4 * o4 + 2][q], w3 = Wt[4 * o4 + 3][q];
#pragma unroll
        for (int k = 0; k < 32; ++k) {
            const f32x4 xv = *reinterpret_cast<const f32x4*>(&xl[ng + 2 * k][4 * o4]);
            acc[k] += xv.x * w0 + xv.y * w1 + xv.z * w2 + xv.w * w3;
        }
    }
    const float b = bl[q];
#pragma unroll
    for (int k = 0; k < 32; ++k)
        out[(size_t)(n0 + ng + 2 * k) * 128 + q] = acc[k] + b;
}

extern "C" void kernel_launch(void* const* d_in, const int* in_sizes, int n_in,
                              void* d_out, int out_size, void* d_ws, size_t ws_size,
                              hipStream_t stream) {
    const float* nf      = (const float*)d_in[0];
    const int*   ei      = (const int*)d_in[1];
    const float* ef      = (const float*)d_in[2];
    const float* W_edge0 = (const float*)d_in[4];
    const float* b_edge0 = (const float*)d_in[5];
    const float* W_root0 = (const float*)d_in[6];
    const float* b_root0 = (const float*)d_in[7];
    const float* gamma0  = (const float*)d_in[8];
    const float* beta0   = (const float*)d_in[9];
    const float* W_edge1 = (const float*)d_in[10];
    const float* b_edge1 = (const float*)d_in[11];
    const float* W_root1 = (const float*)d_in[12];
    const float* b_root1 = (const float*)d_in[13];
    const float* gamma1  = (const float*)d_in[14];
    const float* beta1   = (const float*)d_in[15];
    const float* W_lin   = (const float*)d_in[16];
    const float* b_lin   = (const float*)d_in[17];

    const int N = in_sizes[0] / 64;   // 8192
    const int E = in_sizes[1] / 2;    // 32768
    const int* src = ei;
    const int* dst = ei + E;

    unsigned short* ef_b = (unsigned short*)d_ws;          // E*64
    unsigned short* nf_b = ef_b + (size_t)E * 64;          // N*64
    unsigned short* wfT0 = nf_b + (size_t)N * 64;          // 270336
    unsigned short* wfT1 = wfT0 + 270336;
    unsigned short* xb   = wfT1 + 270336;                  // N*64 (bf16 hidden)
    unsigned short* Gbuf = xb + (size_t)N * 64;            // N*4096
    float* aggr  = (float*)(Gbuf + (size_t)N * 4096);      // N*64
    float* NBbuf = aggr + (size_t)N * 64;                  // N*64
    float* xf    = NBbuf + (size_t)N * 64;                 // N*64 (f32 hidden)
    float* stats = xf + (size_t)N * 64;                    // 128
    float* ssbuf = stats + 128;                            // 128

    const float invN = 1.0f / (float)N;
    const int na4 = E * 64 / 4;          // 524288
    const int nb4 = N * 64 / 4;          // 131072

    cvt_two<<<(na4 + nb4) / 256, 256, 0, stream>>>(ef, ef_b, na4, nf, nf_b);
    build_wfT<<<2 * 270336 / 256, 256, 0, stream>>>(W_edge0, W_root0, b_edge0, wfT0,
                                                    W_edge1, W_root1, b_edge1, wfT1);

    // ---- layer 0 ----
    g_gemm<<<dim3(N / 256, 66), 256, 0, stream>>>(nf_b, wfT0, b_root0, Gbuf, aggr, NBbuf, stats);
    edge_dot<<<E / 32, 256, 0, stream>>>(ef_b, Gbuf, NBbuf, src, dst, aggr);
    bn_stats<<<N / 128, 256, 0, stream>>>(aggr, stats);
    bn_finalize<<<1, 64, 0, stream>>>(stats, gamma0, beta0, ssbuf, invN);
    bn_apply2<<<(nb4 + 255) / 256, 256, 0, stream>>>(aggr, ssbuf, xf, xb, nb4);

    // ---- layer 1 ----
    g_gemm<<<dim3(N / 256, 66), 256, 0, stream>>>(xb, wfT1, b_root1, Gbuf, aggr, NBbuf, stats);
    edge_dot<<<E / 32, 256, 0, stream>>>(ef_b, Gbuf, NBbuf, src, dst, aggr);
    bn_stats<<<N / 128, 256, 0, stream>>>(aggr, stats);
    bn_finalize<<<1, 64, 0, stream>>>(stats, gamma1, beta1, ssbuf, invN);
    bn_apply2<<<(nb4 + 255) / 256, 256, 0, stream>>>(aggr, ssbuf, xf, xb, nb4);

    // ---- final linear ----
    out_kernel<<<N / 64, 256, 0, stream>>>(xf, W_lin, b_lin, (float*)d_out);
}